// Round 2
// baseline (168.886 us; speedup 1.0000x reference)
//
#include <hip/hip_runtime.h>
#include <math.h>

#define BATCH 16384
#define LBL   512
#define HID   768
#define TR    128

typedef unsigned long long u64;
typedef unsigned short ushort_t;
typedef __attribute__((ext_vector_type(8))) short short8;
typedef __attribute__((ext_vector_type(4))) float f32x4;

__device__ __forceinline__ ushort_t f2bf(float f){
  unsigned u = __builtin_bit_cast(unsigned, f);
  u += 0x7FFFu + ((u >> 16) & 1u);
  return (ushort_t)(u >> 16);
}
__device__ __forceinline__ short8 pack8(float4 x, float4 y){
  short8 v;
  v[0]=(short)f2bf(x.x); v[1]=(short)f2bf(x.y); v[2]=(short)f2bf(x.z); v[3]=(short)f2bf(x.w);
  v[4]=(short)f2bf(y.x); v[5]=(short)f2bf(y.y); v[6]=(short)f2bf(y.z); v[7]=(short)f2bf(y.w);
  return v;
}
__device__ __forceinline__ float softplusf(float x){
  return fmaxf(x, 0.0f) + log1pf(expf(-fabsf(x)));
}
__device__ __forceinline__ void gload_lds16(const void* g, void* l){
  __builtin_amdgcn_global_load_lds((const __attribute__((address_space(1))) void*)g,
                                   (__attribute__((address_space(3))) void*)l, 16, 0, 0);
}

// ============ k1: M = W0a@Wt (swizzled bf16) | bias/KV | G = (labe@Wl^T)@W0b^T ============
// Swizzle: element (n, k) of a [128 n][768 k] B-matrix at ((k>>3)<<10) + (n<<3) + (k&7);
// chunk kc (64 k) = contiguous 16 KB at elem offset kc*8192 -> global_load_lds ready.
// G restructured as P=labe@Wl^T (K=768) then G=P@W0b^T (K=128): no dependency on Q,
// so the former k2 merges here as blocks 129..144 (runs parallel to M blocks).
__global__ __launch_bounds__(256) void k1(
    const float* __restrict__ W0, const float* __restrict__ Wt, const float* __restrict__ Wl,
    const float* __restrict__ bt, const float* __restrict__ bl, const float* __restrict__ b0,
    const float* __restrict__ W1, const float* __restrict__ labe,
    ushort_t* __restrict__ Msw, ushort_t* __restrict__ W1B, ushort_t* __restrict__ Gt,
    float* __restrict__ KV, float* __restrict__ out){
  // shared layout (G-blocks): Bs1 [2][8192]us @0 (32768) | As1 [2][32][72]us @32768 (9216)
  //                           Pl [32][136]us @41984 (8704)  => 50688 total
  __shared__ __align__(16) char uni[50688];
  int bi = blockIdx.x, t = threadIdx.x;
  if (bi < 128){
    // ---- M row bi ----
    float* sw = (float*)uni;
    int i = bi;
    if (t < TR) sw[t] = W0[(size_t)i*256 + t];
    if (t < 128) W1B[i*128 + t] = f2bf(W1[i*128 + t]);
    __syncthreads();
    int c = t;
    float a0 = 0.f, a1 = 0.f, a2 = 0.f;
    #pragma unroll 8
    for (int a = 0; a < 128; a++){
      float w = sw[a];
      const float* r = Wt + (size_t)a*HID;
      a0 = fmaf(w, r[c], a0);
      a1 = fmaf(w, r[c+256], a1);
      a2 = fmaf(w, r[c+512], a2);
    }
    int c7 = c & 7;
    Msw[(((c      )>>3)<<10) + (i<<3) + c7] = f2bf(a0);
    Msw[(((c + 256)>>3)<<10) + (i<<3) + c7] = f2bf(a1);
    Msw[(((c + 512)>>3)<<10) + (i<<3) + c7] = f2bf(a2);
  } else if (bi == 128){
    // ---- KV = b0 + W0a@bt + W0b@bl, zero out ----
    if (t < TR){
      float s = b0[t];
      const float* r = W0 + (size_t)t*256;
      for (int a = 0; a < 128; a++) s = fmaf(r[a], bt[a], s);
      for (int a = 0; a < 128; a++) s = fmaf(r[128+a], bl[a], s);
      KV[t] = s;
    }
    if (t == 0) out[0] = 0.f;
  } else {
    // ---- G-block: 32 label rows l0..l0+31 ----
    int gi = bi - 129, l0 = gi * 32;
    int lane = t & 63, wave = t >> 6;          // 4 waves
    int m = lane & 15, q = lane >> 4;
    ushort_t* Bs1 = (ushort_t*)uni;
    ushort_t* As1 = (ushort_t*)(uni + 32768);
    ushort_t* Pl  = (ushort_t*)(uni + 41984);

    // stage-1: P[32][128] = labe[l0..] @ Wl^T, K=768
    int ar = t >> 3, ak = (t & 7) * 8;
    const float* apl = labe + (size_t)(l0 + ar)*HID + ak;
    int aB = t & 127, kh = t >> 7;
    const float* wlr = Wl + (size_t)aB*HID + kh*32;

    float4 ra0 = *(const float4*)apl;
    float4 ra1 = *(const float4*)(apl + 4);
    f32x4 accP[2][2];
    #pragma unroll
    for (int rt = 0; rt < 2; rt++)
      #pragma unroll
      for (int ct = 0; ct < 2; ct++) accP[rt][ct] = (f32x4){0.f,0.f,0.f,0.f};

    for (int c = 0; c < 12; c++){
      int buf = c & 1;
      // stage B chunk: Wl[aB][c*64 + kh*32 + 0..31] -> swizzled bf16
      #pragma unroll
      for (int j = 0; j < 4; j++){
        float4 w0v = *(const float4*)(wlr + c*64 + j*8);
        float4 w1v = *(const float4*)(wlr + c*64 + j*8 + 4);
        *(short8*)(Bs1 + buf*8192 + (kh*4 + j)*1024 + aB*8) = pack8(w0v, w1v);
      }
      // stage A
      *(short8*)(As1 + (size_t)(buf*32 + ar)*72 + ak) = pack8(ra0, ra1);
      __syncthreads();
      if (c < 11){
        ra0 = *(const float4*)(apl + (c+1)*64);
        ra1 = *(const float4*)(apl + (c+1)*64 + 4);
      }
      #pragma unroll
      for (int kcc = 0; kcc < 2; kcc++){
        short8 bfr[2];
        #pragma unroll
        for (int ct = 0; ct < 2; ct++)
          bfr[ct] = *(const short8*)(Bs1 + buf*8192 + (kcc*4 + q)*1024 + (wave*32 + ct*16 + m)*8);
        #pragma unroll
        for (int rt = 0; rt < 2; rt++){
          short8 a = *(const short8*)(As1 + (size_t)(buf*32 + rt*16 + m)*72 + kcc*32 + q*8);
          #pragma unroll
          for (int ct = 0; ct < 2; ct++)
            accP[rt][ct] = __builtin_amdgcn_mfma_f32_16x16x32_bf16(a, bfr[ct], accP[rt][ct], 0, 0, 0);
        }
      }
    }
    // P -> LDS bf16
    #pragma unroll
    for (int rt = 0; rt < 2; rt++)
      #pragma unroll
      for (int ct = 0; ct < 2; ct++){
        int col = wave*32 + ct*16 + m;
        #pragma unroll
        for (int r = 0; r < 4; r++)
          Pl[(size_t)(rt*16 + q*4 + r)*136 + col] = f2bf(accP[rt][ct][r]);
      }
    __syncthreads();   // drain stage-1 reads; publish Pl

    // stage W0b [128 j][128 a] -> swizzled bf16 (overlay Bs1)
    int jB = t & 127, ah = t >> 7;
    const float* w0r = W0 + (size_t)jB*256 + 128 + ah*64;
    #pragma unroll
    for (int g2 = 0; g2 < 8; g2++){
      float4 u0 = *(const float4*)(w0r + g2*8);
      float4 u1 = *(const float4*)(w0r + g2*8 + 4);
      *(short8*)(Bs1 + (ah*8 + g2)*1024 + jB*8) = pack8(u0, u1);
    }
    __syncthreads();

    // stage-2: G[32][128] = P @ W0b^T, K=128
    f32x4 accG[2][2];
    #pragma unroll
    for (int rt = 0; rt < 2; rt++)
      #pragma unroll
      for (int ct = 0; ct < 2; ct++) accG[rt][ct] = (f32x4){0.f,0.f,0.f,0.f};
    #pragma unroll
    for (int kc = 0; kc < 4; kc++){
      short8 bfr[2];
      #pragma unroll
      for (int ct = 0; ct < 2; ct++)
        bfr[ct] = *(const short8*)(Bs1 + (kc*4 + q)*1024 + (wave*32 + ct*16 + m)*8);
      #pragma unroll
      for (int rt = 0; rt < 2; rt++){
        short8 a = *(const short8*)(Pl + (size_t)(rt*16 + m)*136 + kc*32 + q*8);
        #pragma unroll
        for (int ct = 0; ct < 2; ct++)
          accG[rt][ct] = __builtin_amdgcn_mfma_f32_16x16x32_bf16(a, bfr[ct], accG[rt][ct], 0, 0, 0);
      }
    }
    // store Gt[j][l] (transposed)
    #pragma unroll
    for (int rt = 0; rt < 2; rt++)
      #pragma unroll
      for (int ct = 0; ct < 2; ct++){
        int j = wave*32 + ct*16 + m;
        #pragma unroll
        for (int r = 0; r < 4; r++)
          Gt[(size_t)j*LBL + l0 + rt*16 + q*4 + r] = f2bf(accG[rt][ct][r]);
      }
  }
}

// ============ k3: 64-row U-GEMM (32 pos + 32 perm neg) + bitpack + V + h0 + h1 + score ============
// 512 blocks x 512 thr (8 waves), 32 samples/block; wave w owns output cols w*16..w*16+15.
// T4 counted-vmcnt main loop: raw s_barrier + s_waitcnt vmcnt(2) (B-stage stays >=1 iter in
// flight; A reg-prefetch 2-deep). sched_barrier(0) lattice pins VMEM issue order so the FIFO
// count is sound; B(c+1) issued AFTER barrier(c) so buf^1 readers (MFMA(c-1)) are drained.
// tgt ballot done pre-loop (its loads would be forced complete by the first counted wait anyway).
__global__ __launch_bounds__(512, 4) void k3(const float* __restrict__ T, const ushort_t* __restrict__ Msw,
                                          const float* __restrict__ KV, const ushort_t* __restrict__ Gt,
                                          const int* __restrict__ tgt,
                                          const int* __restrict__ perm, const ushort_t* __restrict__ W1b,
                                          const float* __restrict__ b1, const float* __restrict__ W2,
                                          const float* __restrict__ b2, float* __restrict__ out){
  __shared__ __align__(16) char uni[51200];
  __shared__ __align__(16) u64 bitsS[32*10];   // 80B pitch per row
  __shared__ float invs[32];

  int tid = threadIdx.x;
  int lane = tid & 63, wave = tid >> 6;        // wave 0..7
  int m = lane & 15, q = lane >> 4;
  int r0 = blockIdx.x * 32;
  ushort_t* Bs_ = (ushort_t*)uni;              // [2][8192]
  ushort_t* As_ = (ushort_t*)(uni + 32768);    // [2][64][72]

  // ---- issue B(0) ----
  {
    const char* gb = (const char*)Msw;
    char* lb = (char*)Bs_;
    gload_lds16(gb + tid*16,        lb + tid*16);
    gload_lds16(gb + 8192 + tid*16, lb + 8192 + tid*16);
  }
  // ---- issue tgt loads (wave w: rows w*4..w*4+3) ----
  int vv[4][8];
  #pragma unroll
  for (int rr = 0; rr < 4; rr++){
    const int* rp = tgt + (size_t)(r0 + wave*4 + rr)*LBL;
    #pragma unroll
    for (int cc = 0; cc < 8; cc++) vv[rr][cc] = rp[cc*64 + lane];
  }
  // ---- A rows: 0..31 = text[r0+i], 32..63 = text[perm[r0+i]]; prefetch depth 2 ----
  int ar = tid >> 3, ak = (tid & 7) * 8;       // ar 0..63
  int arow = (ar < 32) ? (r0 + ar) : perm[r0 + ar - 32];
  const float* app = T + (size_t)arow*HID + ak;
  float4 aa0[2], aa1[2];
  aa0[0] = *(const float4*)(app);      aa1[0] = *(const float4*)(app + 4);
  aa0[1] = *(const float4*)(app + 64); aa1[1] = *(const float4*)(app + 68);

  // ---- consume tgt: ballot-pack (drains VMEM queue once, pre-loop) ----
  #pragma unroll
  for (int rr = 0; rr < 4; rr++){
    int row = wave*4 + rr;
    int cnt = 0;
    #pragma unroll
    for (int cc = 0; cc < 8; cc++){
      u64 mm = __ballot(vv[rr][cc] != 0);
      if (lane == 0){ ((u64*)((char*)bitsS + row*80))[cc] = mm; cnt += __popcll(mm); }
    }
    if (lane == 0) invs[row] = 1.0f / (float)(cnt < 1 ? 1 : cnt);
  }

  f32x4 acc[4];
  #pragma unroll
  for (int rt = 0; rt < 4; rt++) acc[rt] = (f32x4){0.f,0.f,0.f,0.f};

  #pragma unroll
  for (int c = 0; c < 12; c++){
    int buf = c & 1;
    // step1: pack A(c) -> As_
    *(short8*)(As_ + (size_t)(buf*64 + ar)*72 + ak) = pack8(aa0[buf], aa1[buf]);
    // step2: issue A(c+2) into freed slot
    if (c < 10){
      aa0[buf] = *(const float4*)(app + (c+2)*64);
      aa1[buf] = *(const float4*)(app + (c+2)*64 + 4);
    }
    // step3/4: counted wait + raw barrier (B(c) done; A(c+2)+? may stay in flight)
    __builtin_amdgcn_sched_barrier(0);
    if (c < 10) asm volatile("s_waitcnt vmcnt(2) lgkmcnt(0)" ::: "memory");
    else        asm volatile("s_waitcnt vmcnt(0) lgkmcnt(0)" ::: "memory");
    __builtin_amdgcn_s_barrier();
    __builtin_amdgcn_sched_barrier(0);
    // step5: issue B(c+1) (safe: buf^1 readers drained by barrier(c))
    if (c < 11){
      const char* gb = (const char*)Msw + (size_t)(c+1)*16384;
      char* lb = (char*)(Bs_ + (buf^1)*8192);
      gload_lds16(gb + tid*16,        lb + tid*16);
      gload_lds16(gb + 8192 + tid*16, lb + 8192 + tid*16);
    }
    __builtin_amdgcn_sched_barrier(0);
    // step6: MFMA(c)
    __builtin_amdgcn_s_setprio(1);
    #pragma unroll
    for (int kcc = 0; kcc < 2; kcc++){
      short8 bfr = *(const short8*)(Bs_ + buf*8192 + (kcc*4 + q)*1024 + (wave*16 + m)*8);
      #pragma unroll
      for (int rt = 0; rt < 4; rt++){
        short8 a = *(const short8*)(As_ + (size_t)(buf*64 + rt*16 + m)*72 + kcc*32 + q*8);
        acc[rt] = __builtin_amdgcn_mfma_f32_16x16x32_bf16(a, bfr, acc[rt], 0, 0, 0);
      }
    }
    __builtin_amdgcn_s_setprio(0);
  }

  // ---- V = mask @ G (K=512), Gt prefetch 2-deep ----
  const unsigned char* bits_b = (const unsigned char*)bitsS;
  f32x4 accV[2] = {{0,0,0,0},{0,0,0,0}};
  const ushort_t* gp = Gt + (size_t)(wave*16 + m)*LBL + q*8;
  short8 bv0 = *(const short8*)(gp);
  short8 bv1 = *(const short8*)(gp + 32);
  for (int c = 0; c < 16; c++){
    short8 bn = bv1;
    if (c < 14) bn = *(const short8*)(gp + (size_t)(c+2)*32);
    #pragma unroll
    for (int rt = 0; rt < 2; rt++){
      unsigned bb = bits_b[(rt*16 + m)*80 + c*4 + q];
      short8 a;
      #pragma unroll
      for (int j = 0; j < 8; j++) a[j] = (short)(((bb >> j) & 1u) ? 0x3F80 : 0);
      accV[rt] = __builtin_amdgcn_mfma_f32_16x16x32_bf16(a, bv0, accV[rt], 0, 0, 0);
    }
    bv0 = bv1; bv1 = bn;
  }

  // ---- h0 both branches -> LDS (overlay on uni; GEMM LDS dead now) ----
  __syncthreads();
  ushort_t (*h0s)[136] = (ushort_t(*)[136])uni;   // [64][136]: rows 0-31 pos, 32-63 neg
  float* sred = (float*)(uni + 17408);            // [64][129] floats
  int col = wave*16 + m;
  float kv = KV[col];
  #pragma unroll
  for (int rt = 0; rt < 2; rt++){
    #pragma unroll
    for (int r = 0; r < 4; r++){
      int rowl = rt*16 + q*4 + r;
      float vvv = accV[rt][r] * invs[rowl] + kv;
      h0s[rowl][col]      = f2bf(fmaxf(acc[rt][r]   + vvv, 0.f));
      h0s[32 + rowl][col] = f2bf(fmaxf(acc[rt+2][r] + vvv, 0.f));
    }
  }
  __syncthreads();

  float w2c = W2[col], b1c = b1[col];
  float b2v = b2[0];
  #pragma unroll
  for (int rt2 = 0; rt2 < 4; rt2++){
    f32x4 accH = {0,0,0,0};
    #pragma unroll
    for (int kc = 0; kc < 4; kc++){
      short8 a = *(const short8*)&h0s[rt2*16 + m][kc*32 + q*8];
      short8 b = *(const short8*)(W1b + (size_t)col*TR + kc*32 + q*8);
      accH = __builtin_amdgcn_mfma_f32_16x16x32_bf16(a, b, accH, 0, 0, 0);
    }
    #pragma unroll
    for (int r = 0; r < 4; r++){
      float sp = w2c * fmaxf(accH[r] + b1c, 0.f);
      sred[(size_t)(rt2*16 + q*4 + r)*129 + col] = sp;
    }
  }
  __syncthreads();

  if (tid < 64){
    float s = b2v;
    #pragma unroll
    for (int n = 0; n < 128; n++) s += sred[(size_t)tid*129 + n];
    float val = (tid < 32) ? softplusf(-s) : softplusf(s);   // rows 0-31 = pos branch
    #pragma unroll
    for (int off = 32; off > 0; off >>= 1) val += __shfl_down(val, off);
    if (tid == 0) atomicAdd(out, val * (1.0f / (float)BATCH));
  }
}

extern "C" void kernel_launch(void* const* d_in, const int* in_sizes, int n_in,
                              void* d_out, int out_size, void* d_ws, size_t ws_size,
                              hipStream_t stream){
  const float* text = (const float*)d_in[0];
  const float* labe = (const float*)d_in[1];
  const int*   tgt  = (const int*)  d_in[2];
  const int*   perm = (const int*)  d_in[3];
  const float* Wt   = (const float*)d_in[4];
  const float* bt   = (const float*)d_in[5];
  const float* Wl   = (const float*)d_in[6];
  const float* bl   = (const float*)d_in[7];
  const float* W0   = (const float*)d_in[8];
  const float* b0   = (const float*)d_in[9];
  const float* W1   = (const float*)d_in[10];
  const float* b1   = (const float*)d_in[11];
  const float* W2   = (const float*)d_in[12];
  const float* b2   = (const float*)d_in[13];

  char* wsb = (char*)d_ws;
  size_t off = 0;
  auto alloc = [&](size_t bytes){
    size_t r = off;
    off += (bytes + 255) & ~(size_t)255;
    return r;
  };
  ushort_t* MSW = (ushort_t*)(wsb + alloc((size_t)TR*HID*2));
  ushort_t* GT  = (ushort_t*)(wsb + alloc((size_t)TR*LBL*2));
  ushort_t* W1B = (ushort_t*)(wsb + alloc((size_t)TR*TR*2));
  float*    KV  = (float*)   (wsb + alloc((size_t)TR*4));
  float*    out = (float*)d_out;
  (void)ws_size; (void)in_sizes; (void)n_in; (void)out_size;

  k1<<<145, 256, 0, stream>>>(W0, Wt, Wl, bt, bl, b0, W1, labe, MSW, W1B, GT, KV, out);
  k3<<<512, 512, 0, stream>>>(text, MSW, KV, GT, tgt, perm, W1B, b1, W2, b2, out);
}